// Round 7
// baseline (128.189 us; speedup 1.0000x reference)
//
#include <hip/hip_runtime.h>

typedef float f4 __attribute__((ext_vector_type(4)));
typedef float f2 __attribute__((ext_vector_type(2)));

#define N 1536
#define D 768
#define H 64
#define NN (N * N)

// ---- VOP3P packed-f32 helpers (inline asm, op_sel splat tricks) ----
// NOTE: no v_pk_max_f32 on gfx950 — ReLU done with 2x scalar v_max_f32.
// pre = splat(a.lo) + b
static __device__ __forceinline__ f2 pk_add_sl(f2 a, f2 b) {
    f2 d; asm("v_pk_add_f32 %0, %1, %2 op_sel:[0,0] op_sel_hi:[0,1]"
              : "=v"(d) : "v"(a), "v"(b)); return d;
}
// pre = splat(a.hi) + b
static __device__ __forceinline__ f2 pk_add_sh(f2 a, f2 b) {
    f2 d; asm("v_pk_add_f32 %0, %1, %2 op_sel:[1,0] op_sel_hi:[1,1]"
              : "=v"(d) : "v"(a), "v"(b)); return d;
}
static __device__ __forceinline__ f2 pk_fma(f2 a, f2 b, f2 c) {
    f2 d; asm("v_pk_fma_f32 %0, %1, %2, %3"
              : "=v"(d) : "v"(a), "v"(b), "v"(c)); return d;
}
// acc += a * splat(b.lo)
static __device__ __forceinline__ void pk_fma_acc_sl(f2& acc, f2 a, f2 b) {
    asm("v_pk_fma_f32 %0, %1, %2, %0 op_sel:[0,0,0] op_sel_hi:[1,0,1]"
        : "+v"(acc) : "v"(a), "v"(b));
}
// acc += a * splat(b.hi)
static __device__ __forceinline__ void pk_fma_acc_sh(f2& acc, f2 a, f2 b) {
    asm("v_pk_fma_f32 %0, %1, %2, %0 op_sel:[0,1,0] op_sel_hi:[1,1,1]"
        : "+v"(acc) : "v"(a), "v"(b));
}

// ---------------------------------------------------------------------------
// Kernel 1a: split-K GEMM partials (UNCHANGED - proven numerics).
// ---------------------------------------------------------------------------
__global__ __launch_bounds__(128) void k1_gemm(
    const float* __restrict__ E, const float* __restrict__ pos,
    const float* __restrict__ ppos, const float* __restrict__ W1,
    const float* __restrict__ b1, float* __restrict__ P, int KC)
{
    __shared__ float Es[8][192];

    const int tid = threadIdx.x;
    const int i0  = blockIdx.x * 8;
    const int kcc = blockIdx.y;
    const int k0  = kcc * KC;

    const int hg  = tid & 31;
    const int h0  = hg * 4;
    const int mat = h0 >> 6;
    const int hc  = h0 & 63;
    const int rp  = tid >> 5;
    const float* Wbase = W1 + (size_t)(mat * D + k0) * H + hc;

    f4 acc0 = {0.f, 0.f, 0.f, 0.f};
    f4 acc1 = {0.f, 0.f, 0.f, 0.f};

    for (int ks = 0; ks < KC; ks += 192) {
        if (ks) __syncthreads();
        for (int f = tid; f < 8 * 48; f += 128) {
            int row = f / 48, c = f - row * 48;
            *(f4*)&Es[row][c * 4] =
                *(const f4*)&E[(size_t)(i0 + row) * D + k0 + ks + c * 4];
        }
        __syncthreads();

        const float* Wc  = Wbase + (size_t)ks * H;
        const float* e0p = Es[2 * rp];
        const float* e1p = Es[2 * rp + 1];
        for (int kk = 0; kk < 192; kk += 8) {
#pragma unroll
            for (int u = 0; u < 8; ++u) {
                f4 w = *(const f4*)&Wc[(size_t)(kk + u) * H];
                float e0 = e0p[kk + u], e1 = e1p[kk + u];
                acc0 = __builtin_elementwise_fma((f4){e0, e0, e0, e0}, w, acc0);
                acc1 = __builtin_elementwise_fma((f4){e1, e1, e1, e1}, w, acc1);
            }
        }
    }

    if (kcc == 0) {
        const float* Ws = W1 + (size_t)2 * D * H + hc;
        f4 wp0 = *(const f4*)&Ws[0 * H];
        f4 wp1 = *(const f4*)&Ws[1 * H] + *(const f4*)&Ws[7 * H]; // vdiff fold
        f4 wp2 = *(const f4*)&Ws[2 * H];
        f4 wv0 = *(const f4*)&Ws[4 * H];
        f4 wv1 = *(const f4*)&Ws[5 * H];
        f4 wv2 = *(const f4*)&Ws[6 * H];
        f4 bb  = *(const f4*)&b1[hc];
#pragma unroll
        for (int r = 0; r < 2; ++r) {
            int i = i0 + 2 * rp + r;
            float px = pos[3 * i], py = pos[3 * i + 1], pz = pos[3 * i + 2];
            float vx = px - ppos[3 * i];
            float vy = py - ppos[3 * i + 1];
            float vz = pz - ppos[3 * i + 2];
            f4 g = px * wp0 + py * wp1 + pz * wp2 + vx * wv0 + vy * wv1 + vz * wv2;
            f4 add = (mat == 0) ? (bb - g) : g;
            if (r == 0) acc0 += add; else acc1 += add;
        }
    }

#pragma unroll
    for (int r = 0; r < 2; ++r) {
        int i = i0 + 2 * rp + r;
        f4 a = r ? acc1 : acc0;
#pragma unroll
        for (int c = 0; c < 4; ++c)
            P[(size_t)(kcc * 128 + h0 + c) * N + i] = a[c];
    }
}

// ---------------------------------------------------------------------------
// Kernel 1b: reduce split-K partials (UNCHANGED).
// ---------------------------------------------------------------------------
__global__ __launch_bounds__(256) void k1b_reduce(
    const float* __restrict__ P, float* __restrict__ AB, int nkc)
{
    int idx = blockIdx.x * 256 + threadIdx.x;
    f4 s = {0.f, 0.f, 0.f, 0.f};
    for (int kc = 0; kc < nkc; ++kc)
        s += *(const f4*)&P[(size_t)kc * 128 * N + (size_t)idx * 4];
    *(f4*)&AB[(size_t)idx * 4] = s;
}

// ---------------------------------------------------------------------------
// Kernel 2: 32x32 tile, 128 threads, 2304 blocks. Single-barrier pipeline;
// inner loop forced to v_pk_*_f32 via inline asm (op_sel splats, no movs).
// ---------------------------------------------------------------------------
__global__ __launch_bounds__(128) void k2_main(
    const float* __restrict__ AB, const float* __restrict__ W1,
    const float* __restrict__ W2, const float* __restrict__ b2,
    const float* __restrict__ pos, const float* __restrict__ ppos,
    float* __restrict__ out)
{
    __shared__ float As[64][32];
    __shared__ float Bs[64][32];
    __shared__ float pis[32][3], vis[32][3], pjs[32][3], vjs[32][3];
    __shared__ f2 W2d[64][2];   // [h][0]={w2[0],w2[1]}, [h][1]={w2[2],w2[3]}
    __shared__ f2 w3d[64];      // {w3[h], w3[h]}

    const int tid = threadIdx.x;
    const int i0 = blockIdx.y * 32;
    const int j0 = blockIdx.x * 32;

    // ---- staging: all global loads issue here; ONE barrier total ----
#pragma unroll
    for (int g = 0; g < 4; ++g) {
        int f = g * 128 + tid;
        int h = f >> 3, c = f & 7;
        *(f4*)&As[h][c * 4] = *(const f4*)&AB[(size_t)h * N + i0 + c * 4];
        *(f4*)&Bs[h][c * 4] = *(const f4*)&AB[(size_t)(64 + h) * N + j0 + c * 4];
    }
    if (tid < 32) {
        int i = i0 + tid;
        float px = pos[3 * i], py = pos[3 * i + 1], pz = pos[3 * i + 2];
        pis[tid][0] = px; pis[tid][1] = py; pis[tid][2] = pz;
        vis[tid][0] = px - ppos[3 * i];
        vis[tid][1] = py - ppos[3 * i + 1];
        vis[tid][2] = pz - ppos[3 * i + 2];
    } else if (tid < 64) {
        int t = tid - 32;
        int j = j0 + t;
        float px = pos[3 * j], py = pos[3 * j + 1], pz = pos[3 * j + 2];
        pjs[t][0] = px; pjs[t][1] = py; pjs[t][2] = pz;
        vjs[t][0] = px - ppos[3 * j];
        vjs[t][1] = py - ppos[3 * j + 1];
        vjs[t][2] = pz - ppos[3 * j + 2];
    } else {
        int t = tid - 64;   // 0..63
        f4 w2r = *(const f4*)&W2[t * 4];
        W2d[t][0] = (f2){w2r.x, w2r.y};
        W2d[t][1] = (f2){w2r.z, w2r.w};
        float w3h = W1[(size_t)(2 * D + 3) * H + t];
        w3d[t] = (f2){w3h, w3h};
    }
    __syncthreads();

    const int tx = tid & 15;   // j: tx*2 + 0..1
    const int ty = tid >> 4;   // i: ty*4 + 0..3

    // ---- geometry (registers; numpy op order, threshold-sensitive) ----
    f2 dd[4], dyv[4], clv[4];
    {
#pragma clang fp contract(off)
#pragma unroll
        for (int a = 0; a < 4; ++a) {
#pragma unroll
            for (int b = 0; b < 2; ++b) {
                int il = ty * 4 + a, jl = tx * 2 + b;
                float dx = pjs[jl][0] - pis[il][0];
                float dy = pjs[jl][1] - pis[il][1];
                float dz = pjs[jl][2] - pis[il][2];
                float s = dx * dx;
                s = s + dy * dy;
                s = s + dz * dz;
                float d = sqrtf(s);
                float rvx = vjs[jl][0] - vis[il][0];
                float rvy = vjs[jl][1] - vis[il][1];
                float rvz = vjs[jl][2] - vis[il][2];
                float dot = dx * rvx;
                dot = dot + dy * rvy;
                dot = dot + dz * rvz;
                float cl = -dot / fmaxf(d, 1e-6f);
                dd[a][b] = d; dyv[a][b] = dy; clv[a][b] = cl;
            }
        }
    }

    // ---- MLP inner loop: VOP3P packed f32 (ReLU = 2x v_max_f32) ----
    f2 acc[4][4];
#pragma unroll
    for (int a = 0; a < 4; ++a)
#pragma unroll
        for (int l = 0; l < 4; ++l)
            acc[a][l] = (f2){0.f, 0.f};

#pragma unroll 4
    for (int h = 0; h < 64; ++h) {
        f2 A01 = *(const f2*)&As[h][ty * 4];
        f2 A23 = *(const f2*)&As[h][ty * 4 + 2];
        f2 B2  = *(const f2*)&Bs[h][tx * 2];
        f2 w3v = w3d[h];
        f2 w2p01 = W2d[h][0];
        f2 w2p23 = W2d[h][1];
#pragma unroll
        for (int a = 0; a < 4; ++a) {
            f2 Ap = (a < 2) ? A01 : A23;
            f2 pre = (a & 1) ? pk_add_sh(Ap, B2) : pk_add_sl(Ap, B2);
            f2 hid = __builtin_elementwise_max(pk_fma(dd[a], w3v, pre),
                                               (f2){0.f, 0.f});
            pk_fma_acc_sl(acc[a][0], hid, w2p01);
            pk_fma_acc_sh(acc[a][1], hid, w2p01);
            pk_fma_acc_sl(acc[a][2], hid, w2p23);
            pk_fma_acc_sh(acc[a][3], hid, w2p23);
        }
    }

    // ---- epilogue (pure registers; numerics unchanged) ----
    const f4 B2v = *(const f4*)b2;

#pragma unroll
    for (int a = 0; a < 4; ++a) {
        int i = i0 + ty * 4 + a;
        f2 rt2, cf2, vl2;
#pragma unroll
        for (int b = 0; b < 2; ++b) {
            int j = j0 + tx * 2 + b;
            float l0 = acc[a][0][b] + B2v.x;
            float l1 = acc[a][1][b] + B2v.y;
            float l2 = acc[a][2][b] + B2v.z;
            float l3 = acc[a][3][b] + B2v.w;
            float mx = l0; int bidx = 0;
            if (l1 > mx) { mx = l1; bidx = 1; }
            if (l2 > mx) { mx = l2; bidx = 2; }
            if (l3 > mx) { mx = l3; bidx = 3; }
            float s = expf(l0 - mx);
            s += expf(l1 - mx);
            s += expf(l2 - mx);
            s += expf(l3 - mx);
            float conf = 1.0f / s;   // == max softmax prob

            float d  = dd[a][b];
            float dy = dyv[a][b];
            float cl = clv[a][b];
            bool near = d < 0.25f;
            bool appr = !near && (cl > 0.05f);
            bool flee = !near && !appr && (cl < -0.05f);
            bool above = !near && !appr && !flee && (fabsf(dy) > 0.3f) && (d < 0.5f);
            int rt = near ? 0 : appr ? 1 : flee ? 2 : above ? 3 : bidx;
            float co = near  ? fmaxf(conf, 0.8f)
                     : appr  ? fmaxf(conf, 0.6f)
                     : flee  ? fmaxf(conf, 0.6f)
                     : above ? fmaxf(conf, 0.5f)
                             : conf;
            float vd = ((j > i) && (co > 0.3f)) ? 1.0f : 0.0f;
            rt2[b] = (float)rt;
            cf2[b] = co;
            vl2[b] = vd;
        }
        int col = j0 + tx * 2;
        *(f2*)&out[(size_t)i * N + col]                  = rt2;
        *(f2*)&out[(size_t)NN + (size_t)i * N + col]     = cf2;
        *(f2*)&out[(size_t)2 * NN + (size_t)i * N + col] = vl2;
    }
}

extern "C" void kernel_launch(void* const* d_in, const int* in_sizes, int n_in,
                              void* d_out, int out_size, void* d_ws, size_t ws_size,
                              hipStream_t stream)
{
    const float* E    = (const float*)d_in[0];   // N x 768
    const float* pos  = (const float*)d_in[1];   // N x 3
    const float* ppos = (const float*)d_in[2];   // N x 3
    const float* W1   = (const float*)d_in[3];   // 1544 x 64
    const float* b1   = (const float*)d_in[4];   // 64
    const float* W2   = (const float*)d_in[5];   // 64 x 4
    const float* b2   = (const float*)d_in[6];   // 4
    float* out = (float*)d_out;
    float* P   = (float*)d_ws;

    const size_t part_sz = (size_t)4 * 128 * N;            // floats
    const size_t ab_sz   = (size_t)128 * N;                // floats
    int nkc = (ws_size >= (part_sz + ab_sz) * sizeof(float)) ? 4 : 1;
    int KC  = D / nkc;

    dim3 g1(N / 8, nkc);
    k1_gemm<<<g1, 128, 0, stream>>>(E, pos, ppos, W1, b1, P, KC);

    const float* AB;
    if (nkc > 1) {
        float* ABw = P + part_sz;
        k1b_reduce<<<(128 * N / 4) / 256, 256, 0, stream>>>(P, ABw, nkc);
        AB = ABw;
    } else {
        AB = P;
    }

    dim3 g2(N / 32, N / 32);
    k2_main<<<g2, 128, 0, stream>>>(AB, W1, W2, b2, pos, ppos, out);
}

// Round 8
// 122.554 us; speedup vs baseline: 1.0460x; 1.0460x over previous
//
#include <hip/hip_runtime.h>

typedef float f4 __attribute__((ext_vector_type(4)));
typedef float f2 __attribute__((ext_vector_type(2)));

#define N 1536
#define D 768
#define H 64
#define NN (N * N)

// ---------------------------------------------------------------------------
// Kernel 1a: split-K GEMM partials (UNCHANGED - proven numerics).
// ---------------------------------------------------------------------------
__global__ __launch_bounds__(128) void k1_gemm(
    const float* __restrict__ E, const float* __restrict__ pos,
    const float* __restrict__ ppos, const float* __restrict__ W1,
    const float* __restrict__ b1, float* __restrict__ P, int KC)
{
    __shared__ float Es[8][192];

    const int tid = threadIdx.x;
    const int i0  = blockIdx.x * 8;
    const int kcc = blockIdx.y;
    const int k0  = kcc * KC;

    const int hg  = tid & 31;
    const int h0  = hg * 4;
    const int mat = h0 >> 6;
    const int hc  = h0 & 63;
    const int rp  = tid >> 5;
    const float* Wbase = W1 + (size_t)(mat * D + k0) * H + hc;

    f4 acc0 = {0.f, 0.f, 0.f, 0.f};
    f4 acc1 = {0.f, 0.f, 0.f, 0.f};

    for (int ks = 0; ks < KC; ks += 192) {
        if (ks) __syncthreads();
        for (int f = tid; f < 8 * 48; f += 128) {
            int row = f / 48, c = f - row * 48;
            *(f4*)&Es[row][c * 4] =
                *(const f4*)&E[(size_t)(i0 + row) * D + k0 + ks + c * 4];
        }
        __syncthreads();

        const float* Wc  = Wbase + (size_t)ks * H;
        const float* e0p = Es[2 * rp];
        const float* e1p = Es[2 * rp + 1];
        for (int kk = 0; kk < 192; kk += 8) {
#pragma unroll
            for (int u = 0; u < 8; ++u) {
                f4 w = *(const f4*)&Wc[(size_t)(kk + u) * H];
                float e0 = e0p[kk + u], e1 = e1p[kk + u];
                acc0 = __builtin_elementwise_fma((f4){e0, e0, e0, e0}, w, acc0);
                acc1 = __builtin_elementwise_fma((f4){e1, e1, e1, e1}, w, acc1);
            }
        }
    }

    if (kcc == 0) {
        const float* Ws = W1 + (size_t)2 * D * H + hc;
        f4 wp0 = *(const f4*)&Ws[0 * H];
        f4 wp1 = *(const f4*)&Ws[1 * H] + *(const f4*)&Ws[7 * H]; // vdiff fold
        f4 wp2 = *(const f4*)&Ws[2 * H];
        f4 wv0 = *(const f4*)&Ws[4 * H];
        f4 wv1 = *(const f4*)&Ws[5 * H];
        f4 wv2 = *(const f4*)&Ws[6 * H];
        f4 bb  = *(const f4*)&b1[hc];
#pragma unroll
        for (int r = 0; r < 2; ++r) {
            int i = i0 + 2 * rp + r;
            float px = pos[3 * i], py = pos[3 * i + 1], pz = pos[3 * i + 2];
            float vx = px - ppos[3 * i];
            float vy = py - ppos[3 * i + 1];
            float vz = pz - ppos[3 * i + 2];
            f4 g = px * wp0 + py * wp1 + pz * wp2 + vx * wv0 + vy * wv1 + vz * wv2;
            f4 add = (mat == 0) ? (bb - g) : g;
            if (r == 0) acc0 += add; else acc1 += add;
        }
    }

#pragma unroll
    for (int r = 0; r < 2; ++r) {
        int i = i0 + 2 * rp + r;
        f4 a = r ? acc1 : acc0;
#pragma unroll
        for (int c = 0; c < 4; ++c)
            P[(size_t)(kcc * 128 + h0 + c) * N + i] = a[c];
    }
}

// ---------------------------------------------------------------------------
// Kernel 1b: reduce split-K partials (UNCHANGED).
// ---------------------------------------------------------------------------
__global__ __launch_bounds__(256) void k1b_reduce(
    const float* __restrict__ P, float* __restrict__ AB, int nkc)
{
    int idx = blockIdx.x * 256 + threadIdx.x;
    f4 s = {0.f, 0.f, 0.f, 0.f};
    for (int kc = 0; kc < nkc; ++kc)
        s += *(const f4*)&P[(size_t)kc * 128 * N + (size_t)idx * 4];
    *(f4*)&AB[(size_t)idx * 4] = s;
}

// ---------------------------------------------------------------------------
// Kernel 2: 32x32 tile, 128 threads, 2304 blocks.
// h-CONTIGUOUS LDS layouts: At[ty][h*4+il] (pad 4), Bt[tx][h*2+jb] (pad 2).
//  -> inner-loop DS reads are base+immediate-offset (no address VALU),
//     conflict-free, and B needs one ds_read_b128 per TWO h.
// Weights via uniform global loads (s_load path, R4-proven). One barrier.
// ---------------------------------------------------------------------------
__global__ __launch_bounds__(128) void k2_main(
    const float* __restrict__ AB, const float* __restrict__ W1,
    const float* __restrict__ W2, const float* __restrict__ b2,
    const float* __restrict__ pos, const float* __restrict__ ppos,
    float* __restrict__ out)
{
    __shared__ float At[8][260];    // [ty][h*4 + il], +4 pad: conflict-free
    __shared__ float Bt[16][130];   // [tx][h*2 + jb], +2 pad: conflict-free
    __shared__ float pis[32][3], vis[32][3], pjs[32][3], vjs[32][3];

    const int tid = threadIdx.x;
    const int i0 = blockIdx.y * 32;
    const int j0 = blockIdx.x * 32;

    // ---- staging (transposing writes), ONE barrier total ----
#pragma unroll
    for (int g = 0; g < 4; ++g) {
        int f = g * 128 + tid;
        int h = f >> 3, c = f & 7;
        f4 va = *(const f4*)&AB[(size_t)h * N + i0 + c * 4];
        *(f4*)&At[c][h * 4] = va;
        f4 vb = *(const f4*)&AB[(size_t)(64 + h) * N + j0 + c * 4];
        *(f2*)&Bt[2 * c][h * 2]     = (f2){vb.x, vb.y};
        *(f2*)&Bt[2 * c + 1][h * 2] = (f2){vb.z, vb.w};
    }
    if (tid < 32) {
        int i = i0 + tid;
        float px = pos[3 * i], py = pos[3 * i + 1], pz = pos[3 * i + 2];
        pis[tid][0] = px; pis[tid][1] = py; pis[tid][2] = pz;
        vis[tid][0] = px - ppos[3 * i];
        vis[tid][1] = py - ppos[3 * i + 1];
        vis[tid][2] = pz - ppos[3 * i + 2];
    } else if (tid < 64) {
        int t = tid - 32;
        int j = j0 + t;
        float px = pos[3 * j], py = pos[3 * j + 1], pz = pos[3 * j + 2];
        pjs[t][0] = px; pjs[t][1] = py; pjs[t][2] = pz;
        vjs[t][0] = px - ppos[3 * j];
        vjs[t][1] = py - ppos[3 * j + 1];
        vjs[t][2] = pz - ppos[3 * j + 2];
    }
    __syncthreads();

    const int tx = tid & 15;   // j: tx*2 + 0..1
    const int ty = tid >> 4;   // i: ty*4 + 0..3

    // ---- geometry (registers; numpy op order, threshold-sensitive) ----
    f2 dd[4], dyv[4], clv[4];
    {
#pragma clang fp contract(off)
#pragma unroll
        for (int a = 0; a < 4; ++a) {
#pragma unroll
            for (int b = 0; b < 2; ++b) {
                int il = ty * 4 + a, jl = tx * 2 + b;
                float dx = pjs[jl][0] - pis[il][0];
                float dy = pjs[jl][1] - pis[il][1];
                float dz = pjs[jl][2] - pis[il][2];
                float s = dx * dx;
                s = s + dy * dy;
                s = s + dz * dz;
                float d = sqrtf(s);
                float rvx = vjs[jl][0] - vis[il][0];
                float rvy = vjs[jl][1] - vis[il][1];
                float rvz = vjs[jl][2] - vis[il][2];
                float dot = dx * rvx;
                dot = dot + dy * rvy;
                dot = dot + dz * rvz;
                float cl = -dot / fmaxf(d, 1e-6f);
                dd[a][b] = d; dyv[a][b] = dy; clv[a][b] = cl;
            }
        }
    }

    // ---- MLP inner loop: 2 h per window, immediate-offset DS reads ----
    f2 acc[4][4];
#pragma unroll
    for (int a = 0; a < 4; ++a)
#pragma unroll
        for (int l = 0; l < 4; ++l)
            acc[a][l] = (f2){0.f, 0.f};

    const float* w3p = W1 + (size_t)(2 * D + 3) * H;   // uniform

#pragma unroll 4
    for (int hh = 0; hh < 32; ++hh) {
        const int h = hh * 2;
        f4 A0 = *(const f4*)&At[ty][h * 4];
        f4 A1 = *(const f4*)&At[ty][h * 4 + 4];
        f4 Bp = *(const f4*)&Bt[tx][h * 2];       // B for h and h+1
        float w30 = w3p[h], w31 = w3p[h + 1];
        f4 w2a = *(const f4*)&W2[h * 4];
        f4 w2b = *(const f4*)&W2[h * 4 + 4];

        f2 B20 = (f2){Bp.x, Bp.y};
        f2 B21 = (f2){Bp.z, Bp.w};
        f2 w3v0 = (f2){w30, w30};
        f2 w3v1 = (f2){w31, w31};
#pragma unroll
        for (int a = 0; a < 4; ++a) {
            {   // h
                f2 pre = (f2){A0[a], A0[a]} + B20;
                f2 hid = __builtin_elementwise_fma(dd[a], w3v0, pre);
                hid = __builtin_elementwise_max(hid, (f2){0.f, 0.f});
                acc[a][0] = __builtin_elementwise_fma(hid, (f2){w2a.x, w2a.x}, acc[a][0]);
                acc[a][1] = __builtin_elementwise_fma(hid, (f2){w2a.y, w2a.y}, acc[a][1]);
                acc[a][2] = __builtin_elementwise_fma(hid, (f2){w2a.z, w2a.z}, acc[a][2]);
                acc[a][3] = __builtin_elementwise_fma(hid, (f2){w2a.w, w2a.w}, acc[a][3]);
            }
            {   // h+1
                f2 pre = (f2){A1[a], A1[a]} + B21;
                f2 hid = __builtin_elementwise_fma(dd[a], w3v1, pre);
                hid = __builtin_elementwise_max(hid, (f2){0.f, 0.f});
                acc[a][0] = __builtin_elementwise_fma(hid, (f2){w2b.x, w2b.x}, acc[a][0]);
                acc[a][1] = __builtin_elementwise_fma(hid, (f2){w2b.y, w2b.y}, acc[a][1]);
                acc[a][2] = __builtin_elementwise_fma(hid, (f2){w2b.z, w2b.z}, acc[a][2]);
                acc[a][3] = __builtin_elementwise_fma(hid, (f2){w2b.w, w2b.w}, acc[a][3]);
            }
        }
    }

    // ---- epilogue (pure registers; numerics unchanged) ----
    const f4 B2v = *(const f4*)b2;

#pragma unroll
    for (int a = 0; a < 4; ++a) {
        int i = i0 + ty * 4 + a;
        f2 rt2, cf2, vl2;
#pragma unroll
        for (int b = 0; b < 2; ++b) {
            int j = j0 + tx * 2 + b;
            float l0 = acc[a][0][b] + B2v.x;
            float l1 = acc[a][1][b] + B2v.y;
            float l2 = acc[a][2][b] + B2v.z;
            float l3 = acc[a][3][b] + B2v.w;
            float mx = l0; int bidx = 0;
            if (l1 > mx) { mx = l1; bidx = 1; }
            if (l2 > mx) { mx = l2; bidx = 2; }
            if (l3 > mx) { mx = l3; bidx = 3; }
            float s = expf(l0 - mx);
            s += expf(l1 - mx);
            s += expf(l2 - mx);
            s += expf(l3 - mx);
            float conf = 1.0f / s;   // == max softmax prob

            float d  = dd[a][b];
            float dy = dyv[a][b];
            float cl = clv[a][b];
            bool near = d < 0.25f;
            bool appr = !near && (cl > 0.05f);
            bool flee = !near && !appr && (cl < -0.05f);
            bool above = !near && !appr && !flee && (fabsf(dy) > 0.3f) && (d < 0.5f);
            int rt = near ? 0 : appr ? 1 : flee ? 2 : above ? 3 : bidx;
            float co = near  ? fmaxf(conf, 0.8f)
                     : appr  ? fmaxf(conf, 0.6f)
                     : flee  ? fmaxf(conf, 0.6f)
                     : above ? fmaxf(conf, 0.5f)
                             : conf;
            float vd = ((j > i) && (co > 0.3f)) ? 1.0f : 0.0f;
            rt2[b] = (float)rt;
            cf2[b] = co;
            vl2[b] = vd;
        }
        int col = j0 + tx * 2;
        *(f2*)&out[(size_t)i * N + col]                  = rt2;
        *(f2*)&out[(size_t)NN + (size_t)i * N + col]     = cf2;
        *(f2*)&out[(size_t)2 * NN + (size_t)i * N + col] = vl2;
    }
}

extern "C" void kernel_launch(void* const* d_in, const int* in_sizes, int n_in,
                              void* d_out, int out_size, void* d_ws, size_t ws_size,
                              hipStream_t stream)
{
    const float* E    = (const float*)d_in[0];   // N x 768
    const float* pos  = (const float*)d_in[1];   // N x 3
    const float* ppos = (const float*)d_in[2];   // N x 3
    const float* W1   = (const float*)d_in[3];   // 1544 x 64
    const float* b1   = (const float*)d_in[4];   // 64
    const float* W2   = (const float*)d_in[5];   // 64 x 4
    const float* b2   = (const float*)d_in[6];   // 4
    float* out = (float*)d_out;
    float* P   = (float*)d_ws;

    const size_t part_sz = (size_t)4 * 128 * N;            // floats
    const size_t ab_sz   = (size_t)128 * N;                // floats
    int nkc = (ws_size >= (part_sz + ab_sz) * sizeof(float)) ? 4 : 1;
    int KC  = D / nkc;

    dim3 g1(N / 8, nkc);
    k1_gemm<<<g1, 128, 0, stream>>>(E, pos, ppos, W1, b1, P, KC);

    const float* AB;
    if (nkc > 1) {
        float* ABw = P + part_sz;
        k1b_reduce<<<(128 * N / 4) / 256, 256, 0, stream>>>(P, ABw, nkc);
        AB = ABw;
    } else {
        AB = P;
    }

    dim3 g2(N / 32, N / 32);
    k2_main<<<g2, 128, 0, stream>>>(AB, W1, W2, b2, pos, ppos, out);
}

// Round 9
// 120.517 us; speedup vs baseline: 1.0637x; 1.0169x over previous
//
#include <hip/hip_runtime.h>

typedef float f4 __attribute__((ext_vector_type(4)));
typedef float f2 __attribute__((ext_vector_type(2)));

#define N 1536
#define D 768
#define H 64
#define NN (N * N)

// ---------------------------------------------------------------------------
// Kernel 1a: split-K GEMM partials (UNCHANGED - proven numerics).
// ---------------------------------------------------------------------------
__global__ __launch_bounds__(128) void k1_gemm(
    const float* __restrict__ E, const float* __restrict__ pos,
    const float* __restrict__ ppos, const float* __restrict__ W1,
    const float* __restrict__ b1, float* __restrict__ P, int KC)
{
    __shared__ float Es[8][192];

    const int tid = threadIdx.x;
    const int i0  = blockIdx.x * 8;
    const int kcc = blockIdx.y;
    const int k0  = kcc * KC;

    const int hg  = tid & 31;
    const int h0  = hg * 4;
    const int mat = h0 >> 6;
    const int hc  = h0 & 63;
    const int rp  = tid >> 5;
    const float* Wbase = W1 + (size_t)(mat * D + k0) * H + hc;

    f4 acc0 = {0.f, 0.f, 0.f, 0.f};
    f4 acc1 = {0.f, 0.f, 0.f, 0.f};

    for (int ks = 0; ks < KC; ks += 192) {
        if (ks) __syncthreads();
        for (int f = tid; f < 8 * 48; f += 128) {
            int row = f / 48, c = f - row * 48;
            *(f4*)&Es[row][c * 4] =
                *(const f4*)&E[(size_t)(i0 + row) * D + k0 + ks + c * 4];
        }
        __syncthreads();

        const float* Wc  = Wbase + (size_t)ks * H;
        const float* e0p = Es[2 * rp];
        const float* e1p = Es[2 * rp + 1];
        for (int kk = 0; kk < 192; kk += 8) {
#pragma unroll
            for (int u = 0; u < 8; ++u) {
                f4 w = *(const f4*)&Wc[(size_t)(kk + u) * H];
                float e0 = e0p[kk + u], e1 = e1p[kk + u];
                acc0 = __builtin_elementwise_fma((f4){e0, e0, e0, e0}, w, acc0);
                acc1 = __builtin_elementwise_fma((f4){e1, e1, e1, e1}, w, acc1);
            }
        }
    }

    if (kcc == 0) {
        const float* Ws = W1 + (size_t)2 * D * H + hc;
        f4 wp0 = *(const f4*)&Ws[0 * H];
        f4 wp1 = *(const f4*)&Ws[1 * H] + *(const f4*)&Ws[7 * H]; // vdiff fold
        f4 wp2 = *(const f4*)&Ws[2 * H];
        f4 wv0 = *(const f4*)&Ws[4 * H];
        f4 wv1 = *(const f4*)&Ws[5 * H];
        f4 wv2 = *(const f4*)&Ws[6 * H];
        f4 bb  = *(const f4*)&b1[hc];
#pragma unroll
        for (int r = 0; r < 2; ++r) {
            int i = i0 + 2 * rp + r;
            float px = pos[3 * i], py = pos[3 * i + 1], pz = pos[3 * i + 2];
            float vx = px - ppos[3 * i];
            float vy = py - ppos[3 * i + 1];
            float vz = pz - ppos[3 * i + 2];
            f4 g = px * wp0 + py * wp1 + pz * wp2 + vx * wv0 + vy * wv1 + vz * wv2;
            f4 add = (mat == 0) ? (bb - g) : g;
            if (r == 0) acc0 += add; else acc1 += add;
        }
    }

#pragma unroll
    for (int r = 0; r < 2; ++r) {
        int i = i0 + 2 * rp + r;
        f4 a = r ? acc1 : acc0;
#pragma unroll
        for (int c = 0; c < 4; ++c)
            P[(size_t)(kcc * 128 + h0 + c) * N + i] = a[c];
    }
}

// ---------------------------------------------------------------------------
// Kernel 1b: reduce split-K partials (UNCHANGED).
// ---------------------------------------------------------------------------
__global__ __launch_bounds__(256) void k1b_reduce(
    const float* __restrict__ P, float* __restrict__ AB, int nkc)
{
    int idx = blockIdx.x * 256 + threadIdx.x;
    f4 s = {0.f, 0.f, 0.f, 0.f};
    for (int kc = 0; kc < nkc; ++kc)
        s += *(const f4*)&P[(size_t)kc * 128 * N + (size_t)idx * 4];
    *(f4*)&AB[(size_t)idx * 4] = s;
}

// ---------------------------------------------------------------------------
// Kernel 2: identical to R8 except the softmax epilogue:
//   expf -> __expf (v_exp_f32 path), 1/s -> v_rcp_f32.
// conf perturbation ~3e-7, four orders under the demonstrated 0.0039 margin.
// dist/closing chain untouched (threshold-critical, bit-identical).
// ---------------------------------------------------------------------------
__global__ __launch_bounds__(128) void k2_main(
    const float* __restrict__ AB, const float* __restrict__ W1,
    const float* __restrict__ W2, const float* __restrict__ b2,
    const float* __restrict__ pos, const float* __restrict__ ppos,
    float* __restrict__ out)
{
    __shared__ float At[8][260];    // [ty][h*4 + il], +4 pad: conflict-free
    __shared__ float Bt[16][130];   // [tx][h*2 + jb], +2 pad: conflict-free
    __shared__ float pis[32][3], vis[32][3], pjs[32][3], vjs[32][3];

    const int tid = threadIdx.x;
    const int i0 = blockIdx.y * 32;
    const int j0 = blockIdx.x * 32;

    // ---- staging (transposing writes), ONE barrier total ----
#pragma unroll
    for (int g = 0; g < 4; ++g) {
        int f = g * 128 + tid;
        int h = f >> 3, c = f & 7;
        f4 va = *(const f4*)&AB[(size_t)h * N + i0 + c * 4];
        *(f4*)&At[c][h * 4] = va;
        f4 vb = *(const f4*)&AB[(size_t)(64 + h) * N + j0 + c * 4];
        *(f2*)&Bt[2 * c][h * 2]     = (f2){vb.x, vb.y};
        *(f2*)&Bt[2 * c + 1][h * 2] = (f2){vb.z, vb.w};
    }
    if (tid < 32) {
        int i = i0 + tid;
        float px = pos[3 * i], py = pos[3 * i + 1], pz = pos[3 * i + 2];
        pis[tid][0] = px; pis[tid][1] = py; pis[tid][2] = pz;
        vis[tid][0] = px - ppos[3 * i];
        vis[tid][1] = py - ppos[3 * i + 1];
        vis[tid][2] = pz - ppos[3 * i + 2];
    } else if (tid < 64) {
        int t = tid - 32;
        int j = j0 + t;
        float px = pos[3 * j], py = pos[3 * j + 1], pz = pos[3 * j + 2];
        pjs[t][0] = px; pjs[t][1] = py; pjs[t][2] = pz;
        vjs[t][0] = px - ppos[3 * j];
        vjs[t][1] = py - ppos[3 * j + 1];
        vjs[t][2] = pz - ppos[3 * j + 2];
    }
    __syncthreads();

    const int tx = tid & 15;   // j: tx*2 + 0..1
    const int ty = tid >> 4;   // i: ty*4 + 0..3

    // ---- geometry (registers; numpy op order, threshold-sensitive) ----
    f2 dd[4], dyv[4], clv[4];
    {
#pragma clang fp contract(off)
#pragma unroll
        for (int a = 0; a < 4; ++a) {
#pragma unroll
            for (int b = 0; b < 2; ++b) {
                int il = ty * 4 + a, jl = tx * 2 + b;
                float dx = pjs[jl][0] - pis[il][0];
                float dy = pjs[jl][1] - pis[il][1];
                float dz = pjs[jl][2] - pis[il][2];
                float s = dx * dx;
                s = s + dy * dy;
                s = s + dz * dz;
                float d = sqrtf(s);
                float rvx = vjs[jl][0] - vis[il][0];
                float rvy = vjs[jl][1] - vis[il][1];
                float rvz = vjs[jl][2] - vis[il][2];
                float dot = dx * rvx;
                dot = dot + dy * rvy;
                dot = dot + dz * rvz;
                float cl = -dot / fmaxf(d, 1e-6f);
                dd[a][b] = d; dyv[a][b] = dy; clv[a][b] = cl;
            }
        }
    }

    // ---- MLP inner loop: 2 h per window, immediate-offset DS reads ----
    f2 acc[4][4];
#pragma unroll
    for (int a = 0; a < 4; ++a)
#pragma unroll
        for (int l = 0; l < 4; ++l)
            acc[a][l] = (f2){0.f, 0.f};

    const float* w3p = W1 + (size_t)(2 * D + 3) * H;   // uniform

#pragma unroll 4
    for (int hh = 0; hh < 32; ++hh) {
        const int h = hh * 2;
        f4 A0 = *(const f4*)&At[ty][h * 4];
        f4 A1 = *(const f4*)&At[ty][h * 4 + 4];
        f4 Bp = *(const f4*)&Bt[tx][h * 2];       // B for h and h+1
        float w30 = w3p[h], w31 = w3p[h + 1];
        f4 w2a = *(const f4*)&W2[h * 4];
        f4 w2b = *(const f4*)&W2[h * 4 + 4];

        f2 B20 = (f2){Bp.x, Bp.y};
        f2 B21 = (f2){Bp.z, Bp.w};
        f2 w3v0 = (f2){w30, w30};
        f2 w3v1 = (f2){w31, w31};
#pragma unroll
        for (int a = 0; a < 4; ++a) {
            {   // h
                f2 pre = (f2){A0[a], A0[a]} + B20;
                f2 hid = __builtin_elementwise_fma(dd[a], w3v0, pre);
                hid = __builtin_elementwise_max(hid, (f2){0.f, 0.f});
                acc[a][0] = __builtin_elementwise_fma(hid, (f2){w2a.x, w2a.x}, acc[a][0]);
                acc[a][1] = __builtin_elementwise_fma(hid, (f2){w2a.y, w2a.y}, acc[a][1]);
                acc[a][2] = __builtin_elementwise_fma(hid, (f2){w2a.z, w2a.z}, acc[a][2]);
                acc[a][3] = __builtin_elementwise_fma(hid, (f2){w2a.w, w2a.w}, acc[a][3]);
            }
            {   // h+1
                f2 pre = (f2){A1[a], A1[a]} + B21;
                f2 hid = __builtin_elementwise_fma(dd[a], w3v1, pre);
                hid = __builtin_elementwise_max(hid, (f2){0.f, 0.f});
                acc[a][0] = __builtin_elementwise_fma(hid, (f2){w2b.x, w2b.x}, acc[a][0]);
                acc[a][1] = __builtin_elementwise_fma(hid, (f2){w2b.y, w2b.y}, acc[a][1]);
                acc[a][2] = __builtin_elementwise_fma(hid, (f2){w2b.z, w2b.z}, acc[a][2]);
                acc[a][3] = __builtin_elementwise_fma(hid, (f2){w2b.w, w2b.w}, acc[a][3]);
            }
        }
    }

    // ---- epilogue: fast exp/rcp (conf-only path; margin-safe) ----
    const f4 B2v = *(const f4*)b2;

#pragma unroll
    for (int a = 0; a < 4; ++a) {
        int i = i0 + ty * 4 + a;
        f2 rt2, cf2, vl2;
#pragma unroll
        for (int b = 0; b < 2; ++b) {
            int j = j0 + tx * 2 + b;
            float l0 = acc[a][0][b] + B2v.x;
            float l1 = acc[a][1][b] + B2v.y;
            float l2 = acc[a][2][b] + B2v.z;
            float l3 = acc[a][3][b] + B2v.w;
            float mx = l0; int bidx = 0;
            if (l1 > mx) { mx = l1; bidx = 1; }
            if (l2 > mx) { mx = l2; bidx = 2; }
            if (l3 > mx) { mx = l3; bidx = 3; }
            float s = __expf(l0 - mx);
            s += __expf(l1 - mx);
            s += __expf(l2 - mx);
            s += __expf(l3 - mx);
            float conf = __builtin_amdgcn_rcpf(s);   // == max softmax prob

            float d  = dd[a][b];
            float dy = dyv[a][b];
            float cl = clv[a][b];
            bool near = d < 0.25f;
            bool appr = !near && (cl > 0.05f);
            bool flee = !near && !appr && (cl < -0.05f);
            bool above = !near && !appr && !flee && (fabsf(dy) > 0.3f) && (d < 0.5f);
            int rt = near ? 0 : appr ? 1 : flee ? 2 : above ? 3 : bidx;
            float co = near  ? fmaxf(conf, 0.8f)
                     : appr  ? fmaxf(conf, 0.6f)
                     : flee  ? fmaxf(conf, 0.6f)
                     : above ? fmaxf(conf, 0.5f)
                             : conf;
            float vd = ((j > i) && (co > 0.3f)) ? 1.0f : 0.0f;
            rt2[b] = (float)rt;
            cf2[b] = co;
            vl2[b] = vd;
        }
        int col = j0 + tx * 2;
        *(f2*)&out[(size_t)i * N + col]                  = rt2;
        *(f2*)&out[(size_t)NN + (size_t)i * N + col]     = cf2;
        *(f2*)&out[(size_t)2 * NN + (size_t)i * N + col] = vl2;
    }
}

extern "C" void kernel_launch(void* const* d_in, const int* in_sizes, int n_in,
                              void* d_out, int out_size, void* d_ws, size_t ws_size,
                              hipStream_t stream)
{
    const float* E    = (const float*)d_in[0];   // N x 768
    const float* pos  = (const float*)d_in[1];   // N x 3
    const float* ppos = (const float*)d_in[2];   // N x 3
    const float* W1   = (const float*)d_in[3];   // 1544 x 64
    const float* b1   = (const float*)d_in[4];   // 64
    const float* W2   = (const float*)d_in[5];   // 64 x 4
    const float* b2   = (const float*)d_in[6];   // 4
    float* out = (float*)d_out;
    float* P   = (float*)d_ws;

    const size_t part_sz = (size_t)4 * 128 * N;            // floats
    const size_t ab_sz   = (size_t)128 * N;                // floats
    int nkc = (ws_size >= (part_sz + ab_sz) * sizeof(float)) ? 4 : 1;
    int KC  = D / nkc;

    dim3 g1(N / 8, nkc);
    k1_gemm<<<g1, 128, 0, stream>>>(E, pos, ppos, W1, b1, P, KC);

    const float* AB;
    if (nkc > 1) {
        float* ABw = P + part_sz;
        k1b_reduce<<<(128 * N / 4) / 256, 256, 0, stream>>>(P, ABw, nkc);
        AB = ABw;
    } else {
        AB = P;
    }

    dim3 g2(N / 32, N / 32);
    k2_main<<<g2, 128, 0, stream>>>(AB, W1, W2, b2, pos, ppos, out);
}